// Round 1
// 15209.146 us; speedup vs baseline: 2.5020x; 2.5020x over previous
//
#include <hip/hip_runtime.h>
#include <cstdint>
#include <cstddef>

#define FLAG_BIAS 1
#define FLAG_GELU 2
#define FLAG_ACC  4
#define FLAG_PAIR 8

static constexpr int Dm   = 768;
static constexpr int Ssz  = 500;

typedef _Float16 f16x8 __attribute__((ext_vector_type(8)));
typedef _Float16 f16x4 __attribute__((ext_vector_type(4)));
typedef _Float16 f16x2 __attribute__((ext_vector_type(2)));
typedef float    f32x4 __attribute__((ext_vector_type(4)));

__device__ __forceinline__ float gelu_f(float v) {
  return 0.5f * v * (1.0f + erff(v * 0.7071067811865475f));
}

// async global->LDS, 16B per lane; LDS dest is wave-uniform base + lane*16
__device__ __forceinline__ void glds16B(const void* g, void* l) {
  __builtin_amdgcn_global_load_lds(
      (__attribute__((address_space(1))) void*)(uintptr_t)g,
      (__attribute__((address_space(3))) void*)(uintptr_t)l,
      16, 0, 0);
}

// ---------------- conv (patch embed) + pos embed -> tok ----------------
__global__ __launch_bounds__(256) void conv_kernel(const float* __restrict__ x,
                                                   const float* __restrict__ cw,
                                                   const float* __restrict__ cb,
                                                   const float* __restrict__ pe,
                                                   float* __restrict__ tok) {
  __shared__ float ps[16][256];
  int b = blockIdx.y;
  int s0 = blockIdx.x * 16;
  int tid = threadIdx.x;
  for (int idxv = tid; idxv < 16 * 256; idxv += 256) {
    int sl = idxv >> 8, k = idxv & 255;
    int s = s0 + sl;
    int f = k >> 2, t = k & 3;
    ps[sl][k] = (s < Ssz) ? x[b * 128000 + f * 2000 + 4 * s + t] : 0.f;
  }
  __syncthreads();
  for (int d = tid; d < Dm; d += 256) {
    float acc[16];
#pragma unroll
    for (int sl = 0; sl < 16; ++sl) acc[sl] = 0.f;
    for (int k = 0; k < 256; ++k) {
      float w = cw[d * 256 + k];
#pragma unroll
      for (int sl = 0; sl < 16; ++sl) acc[sl] += w * ps[sl][k];
    }
    float bb = cb[d];
    for (int sl = 0; sl < 16; ++sl) {
      int s = s0 + sl;
      if (s < Ssz)
        tok[((size_t)b * Ssz + s) * Dm + d] = acc[sl] + bb + pe[s * Dm + d];
    }
  }
}

// ---------------- layernorm over D=768 ----------------
__device__ __forceinline__ float block_sum_256(float v, float* red) {
#pragma unroll
  for (int o = 32; o > 0; o >>= 1) v += __shfl_down(v, o);
  int lane = threadIdx.x & 63, w = threadIdx.x >> 6;
  if (lane == 0) red[w] = v;
  __syncthreads();
  return red[0] + red[1] + red[2] + red[3];
}

__global__ __launch_bounds__(256) void ln_kernel(const float* __restrict__ in,
                                                 const float* __restrict__ sc,
                                                 const float* __restrict__ bi,
                                                 float* __restrict__ out) {
  __shared__ float redA[4], redB[4];
  int r = blockIdx.x;
  const float* xr = in + (size_t)r * Dm;
  int tid = threadIdx.x;
  float v[3];
  float sum = 0.f;
#pragma unroll
  for (int i = 0; i < 3; ++i) { v[i] = xr[tid + i * 256]; sum += v[i]; }
  float tot = block_sum_256(sum, redA);
  float mu = tot * (1.f / 768.f);
  float var = 0.f;
#pragma unroll
  for (int i = 0; i < 3; ++i) { float d = v[i] - mu; var += d * d; }
  float vt = block_sum_256(var, redB) * (1.f / 768.f);
  float rs = rsqrtf(vt + 1e-5f);
  float* orow = out + (size_t)r * Dm;
#pragma unroll
  for (int i = 0; i < 3; ++i) {
    int e = tid + i * 256;
    orow[e] = (v[i] - mu) * rs * sc[e] + bi[e];
  }
}

// ---------------- fp32 tiled GEMM (kept for the tiny gate GEMM only) ----------------
__device__ __forceinline__ void gemm_tile_body(const float* __restrict__ A,
                                               const float* __restrict__ Bm,
                                               int M, int N, int Kd, int ldb,
                                               int row0, int col0,
                                               float (&As)[16][68], float (&Bs)[16][68],
                                               float (&acc)[4][4]) {
  int tid = threadIdx.x;
  int aRow = tid >> 2, aCol = (tid & 3) * 4;
  int bRow = tid >> 4, bCol = (tid & 15) * 4;
  int tx = tid & 15, ty = tid >> 4;
  int gr = row0 + aRow;
  const float* Arow = (gr < M) ? (A + (size_t)gr * Kd) : nullptr;
  for (int k0 = 0; k0 < Kd; k0 += 16) {
#pragma unroll
    for (int j = 0; j < 4; ++j)
      As[aCol + j][aRow] = Arow ? Arow[k0 + aCol + j] : 0.f;
    const float* Brow = Bm + (size_t)(k0 + bRow) * ldb + col0;
#pragma unroll
    for (int j = 0; j < 4; ++j) {
      int c = bCol + j;
      Bs[bRow][c] = (col0 + c < N) ? Brow[c] : 0.f;
    }
    __syncthreads();
#pragma unroll
    for (int kk = 0; kk < 16; ++kk) {
      const float4 av = *reinterpret_cast<const float4*>(&As[kk][ty * 4]);
      const float4 bv = *reinterpret_cast<const float4*>(&Bs[kk][tx * 4]);
      float a[4] = {av.x, av.y, av.z, av.w};
      float b[4] = {bv.x, bv.y, bv.z, bv.w};
#pragma unroll
      for (int i = 0; i < 4; ++i)
#pragma unroll
        for (int j = 0; j < 4; ++j)
          acc[i][j] += a[i] * b[j];
    }
    __syncthreads();
  }
}

__global__ __launch_bounds__(256) void gemm_kernel(const float* __restrict__ A,
                                                   const float* __restrict__ Bm,
                                                   const float* __restrict__ bias,
                                                   float* __restrict__ C,
                                                   int M, int N, int Kd, int ldb, int ldc,
                                                   int flags) {
  __shared__ float As[16][68], Bs[16][68];
  float acc[4][4] = {{0.f}};
  int row0 = blockIdx.y * 64, col0 = blockIdx.x * 64;
  gemm_tile_body(A, Bm, M, N, Kd, ldb, row0, col0, As, Bs, acc);
  int tx = threadIdx.x & 15, ty = threadIdx.x >> 4;
#pragma unroll
  for (int i = 0; i < 4; ++i) {
    int r = row0 + ty * 4 + i;
    if (r >= M) continue;
#pragma unroll
    for (int j = 0; j < 4; ++j) {
      int c = col0 + tx * 4 + j;
      if (c >= N) continue;
      float v = acc[i][j];
      if (flags & FLAG_BIAS) v += bias[c];
      if (flags & FLAG_GELU) v = gelu_f(v);
      float* p = C + (size_t)r * ldc + c;
      if (flags & FLAG_ACC) *p += v; else *p = v;
    }
  }
}

// ---------------- weight convert+transpose: W[K][N] fp32 -> Wt[N][K] fp16 ----------------
__global__ __launch_bounds__(256) void wt_kernel(const float* __restrict__ W,
                                                 _Float16* __restrict__ Wt,
                                                 int K, int N) {
  __shared__ float s[32][33];
  size_t moff = (size_t)blockIdx.z * K * N;
  W += moff; Wt += moff;
  int k0 = blockIdx.y * 32, n0 = blockIdx.x * 32;
  int t = threadIdx.x;
#pragma unroll
  for (int i = 0; i < 4; ++i) {
    int idx = t + 256 * i;
    int r = idx >> 5, c = idx & 31;
    s[r][c] = W[(size_t)(k0 + r) * N + n0 + c];
  }
  __syncthreads();
#pragma unroll
  for (int i = 0; i < 2; ++i) {
    int idx = t + 256 * i;
    int n = idx >> 4, kp = idx & 15;
    f16x2 v;
    v.x = (_Float16)s[2 * kp][n];
    v.y = (_Float16)s[2 * kp + 1][n];
    *reinterpret_cast<f16x2*>(&Wt[(size_t)(n0 + n) * K + k0 + 2 * kp]) = v;
  }
}

// ---------------- activation hi/lo fp16 split ----------------
__global__ __launch_bounds__(256) void pairconv_kernel(const float* __restrict__ in,
                                                       _Float16* __restrict__ oh,
                                                       _Float16* __restrict__ ol, int n4) {
  int i = blockIdx.x * 256 + threadIdx.x;
  if (i >= n4) return;
  float4 v = reinterpret_cast<const float4*>(in)[i];
  float f[4] = {v.x, v.y, v.z, v.w};
  f16x4 h, lo;
#pragma unroll
  for (int j = 0; j < 4; ++j) {
    _Float16 hh = (_Float16)f[j];
    h[j] = hh;
    lo[j] = (_Float16)(f[j] - (float)hh);
  }
  *reinterpret_cast<f16x4*>(&oh[4 * i]) = h;
  *reinterpret_cast<f16x4*>(&ol[4 * i]) = lo;
}

// ---------------- fp16 MFMA GEMM, compensated: C = (Ah+Al)[M,K] * Bt[N,K]^T ----------------
// 128x128 tile, BK=32, 4 waves (64x64 each), 16x16x32_f16 MFMA, fp32 acc.
struct alignas(16) GemmSmem {
  _Float16 Ah[4096];   // [128][32]
  _Float16 Al[4096];   // [128][32]
  _Float16 B[4096];    // [128 cols][32 k]  (Bt rows)
};

__device__ __forceinline__ void gemm16_body(
    const _Float16* __restrict__ Ah, const _Float16* __restrict__ Al,
    const _Float16* __restrict__ Bt, const float* __restrict__ bias,
    float* __restrict__ C, _Float16* __restrict__ Ch, _Float16* __restrict__ Cl,
    int M, int Kd, int lda, int ldb, int ldc,
    int row0, int col0, float scale, int flags, GemmSmem& sm) {
  const int tid = threadIdx.x;
  const int w = tid >> 6, l = tid & 63;
  f32x4 acc[4][4] = {};
  const int lrow = l >> 2;          // 0..15 : row within 16-row chunk
  const int lk   = (l & 3) << 3;    // 0,8,16,24 : k offset within 32
  const int koff = (l >> 4) << 3;   // frag: 8 k-contig elems per lane
  const int fr   = l & 15;          // frag row/col lane part
  const int Mm1 = M - 1;
  for (int k0 = 0; k0 < Kd; k0 += 32) {
#pragma unroll
    for (int c = 0; c < 2; ++c) {
      const int ch = (w << 1) + c;           // chunk 0..7 (16 rows each)
      int ar = row0 + ch * 16 + lrow;
      ar = (ar > Mm1) ? Mm1 : ar;            // M-tail: clamp (dead rows)
      const size_t aoff = (size_t)ar * lda + (k0 + lk);
      glds16B(Ah + aoff, &sm.Ah[ch << 9]);
      glds16B(Al + aoff, &sm.Al[ch << 9]);
      const int bc = col0 + ch * 16 + lrow;  // N always multiple of 128
      glds16B(Bt + (size_t)bc * ldb + (k0 + lk), &sm.B[ch << 9]);
    }
    __syncthreads();
    f16x8 bfrag[4];
#pragma unroll
    for (int cf = 0; cf < 4; ++cf) {
      const int col = (w & 1) * 64 + cf * 16 + fr;
      bfrag[cf] = *reinterpret_cast<const f16x8*>(&sm.B[col * 32 + koff]);
    }
#pragma unroll
    for (int mf = 0; mf < 4; ++mf) {
      const int row = (w >> 1) * 64 + mf * 16 + fr;
      const f16x8 ah = *reinterpret_cast<const f16x8*>(&sm.Ah[row * 32 + koff]);
      const f16x8 al = *reinterpret_cast<const f16x8*>(&sm.Al[row * 32 + koff]);
#pragma unroll
      for (int cf = 0; cf < 4; ++cf) {
        acc[mf][cf] = __builtin_amdgcn_mfma_f32_16x16x32_f16(ah, bfrag[cf], acc[mf][cf], 0, 0, 0);
        acc[mf][cf] = __builtin_amdgcn_mfma_f32_16x16x32_f16(al, bfrag[cf], acc[mf][cf], 0, 0, 0);
      }
    }
    __syncthreads();
  }
  // epilogue: C/D layout col=lane&15, row=(lane>>4)*4+j  [m89-verified]
  const int rb = row0 + (w >> 1) * 64 + ((l >> 4) << 2);
  const int cb = col0 + (w & 1) * 64 + fr;
#pragma unroll
  for (int mf = 0; mf < 4; ++mf) {
#pragma unroll
    for (int j = 0; j < 4; ++j) {
      const int r = rb + mf * 16 + j;
      if (r >= M) continue;
#pragma unroll
      for (int cf = 0; cf < 4; ++cf) {
        const int c = cb + cf * 16;
        float v = acc[mf][cf][j];
        if (flags & FLAG_BIAS) v += bias[c];
        if (flags & FLAG_GELU) v = gelu_f(v);
        v *= scale;
        const size_t o = (size_t)r * ldc + c;
        if (flags & FLAG_PAIR) {
          _Float16 h = (_Float16)v;
          Ch[o] = h;
          Cl[o] = (_Float16)(v - (float)h);
        } else if (flags & FLAG_ACC) {
          C[o] += v;
        } else {
          C[o] = v;
        }
      }
    }
  }
}

__global__ __launch_bounds__(256) void gemm16_kernel(
    const _Float16* __restrict__ Ah, const _Float16* __restrict__ Al,
    const _Float16* __restrict__ Bt, const float* __restrict__ bias,
    float* __restrict__ C, _Float16* __restrict__ Ch, _Float16* __restrict__ Cl,
    int M, int Kd, int lda, int ldb, int ldc, float scale, int flags) {
  __shared__ GemmSmem sm;
  gemm16_body(Ah, Al, Bt, bias, C, Ch, Cl, M, Kd, lda, ldb, ldc,
              blockIdx.y * 128, blockIdx.x * 128, scale, flags, sm);
}

__global__ __launch_bounds__(256) void moe1_16_kernel(
    const _Float16* __restrict__ xh, const _Float16* __restrict__ xl,
    const _Float16* __restrict__ ew1t, const float* __restrict__ eb1,
    const int* __restrict__ idx, _Float16* __restrict__ hidh,
    _Float16* __restrict__ hidl, int ksel) {
  __shared__ GemmSmem sm;
  int b = blockIdx.z;
  int e = idx[b * 4 + ksel];
  gemm16_body(xh + (size_t)b * Ssz * Dm, xl + (size_t)b * Ssz * Dm,
              ew1t + (size_t)e * 1536 * 768, eb1 + (size_t)e * 1536,
              nullptr, hidh + (size_t)b * Ssz * 1536, hidl + (size_t)b * Ssz * 1536,
              Ssz, 768, 768, 768, 1536,
              blockIdx.y * 128, blockIdx.x * 128, 1.f,
              FLAG_BIAS | FLAG_GELU | FLAG_PAIR, sm);
}

__global__ __launch_bounds__(256) void moe2_16_kernel(
    const _Float16* __restrict__ hidh, const _Float16* __restrict__ hidl,
    const _Float16* __restrict__ ew2t, const float* __restrict__ eb2,
    const int* __restrict__ idx, const float* __restrict__ wgt,
    float* __restrict__ tok, int ksel) {
  __shared__ GemmSmem sm;
  int b = blockIdx.z;
  int e = idx[b * 4 + ksel];
  float wv = wgt[b * 4 + ksel];
  gemm16_body(hidh + (size_t)b * Ssz * 1536, hidl + (size_t)b * Ssz * 1536,
              ew2t + (size_t)e * 768 * 1536, eb2 + (size_t)e * 768,
              tok + (size_t)b * Ssz * Dm, nullptr, nullptr,
              Ssz, 1536, 1536, 1536, 768,
              blockIdx.y * 128, blockIdx.x * 128, wv,
              FLAG_BIAS | FLAG_ACC, sm);
}

// ---------------- attention (unchanged; next-round target) ----------------
__global__ __launch_bounds__(256) void attn_kernel(const float* __restrict__ qkv,
                                                   float* __restrict__ out) {
  __shared__ float q_s[16][65];
  __shared__ float kv_s[64][65];
  __shared__ float p_s[16][512];
  int b = blockIdx.z, h = blockIdx.y, qt = blockIdx.x;
  int tid = threadIdx.x, lane = tid & 63, wv = tid >> 6;
  int q0 = qt * 16;
  for (int ql = wv; ql < 16; ql += 4) {
    int s = q0 + ql;
    q_s[ql][lane] = (s < Ssz) ? qkv[((size_t)b * Ssz + s) * 2304 + h * 64 + lane] : 0.f;
  }
  __syncthreads();
  for (int kb = 0; kb < 8; ++kb) {
    int k0 = kb * 64;
    for (int i = wv; i < 64; i += 4) {
      int s = k0 + i;
      kv_s[i][lane] = (s < Ssz) ? qkv[((size_t)b * Ssz + s) * 2304 + 768 + h * 64 + lane] : 0.f;
    }
    __syncthreads();
#pragma unroll
    for (int j = 0; j < 4; ++j) {
      int ql = wv * 4 + j;
      float s = 0.f;
#pragma unroll 16
      for (int d = 0; d < 64; ++d) s += q_s[ql][d] * kv_s[lane][d];
      p_s[ql][k0 + lane] = s * 0.125f;
    }
    __syncthreads();
  }
  float rcp[4];
#pragma unroll
  for (int j = 0; j < 4; ++j) {
    int ql = wv * 4 + j;
    float m = -1e30f;
#pragma unroll
    for (int kb = 0; kb < 8; ++kb) {
      int k = kb * 64 + lane;
      if (k < Ssz) m = fmaxf(m, p_s[ql][k]);
    }
#pragma unroll
    for (int o = 32; o > 0; o >>= 1) m = fmaxf(m, __shfl_xor(m, o));
    float sum = 0.f;
#pragma unroll
    for (int kb = 0; kb < 8; ++kb) {
      int k = kb * 64 + lane;
      float p = (k < Ssz) ? expf(p_s[ql][k] - m) : 0.f;
      p_s[ql][k] = p;
      sum += p;
    }
#pragma unroll
    for (int o = 32; o > 0; o >>= 1) sum += __shfl_xor(sum, o);
    rcp[j] = 1.f / sum;
  }
  __syncthreads();
  float o4[4] = {0.f, 0.f, 0.f, 0.f};
  for (int kb = 0; kb < 8; ++kb) {
    int k0 = kb * 64;
    for (int i = wv; i < 64; i += 4) {
      int s = k0 + i;
      kv_s[i][lane] = (s < Ssz) ? qkv[((size_t)b * Ssz + s) * 2304 + 1536 + h * 64 + lane] : 0.f;
    }
    __syncthreads();
#pragma unroll 8
    for (int i = 0; i < 64; ++i) {
      float vv = kv_s[i][lane];
      int k = k0 + i;
#pragma unroll
      for (int j = 0; j < 4; ++j) o4[j] += p_s[wv * 4 + j][k] * vv;
    }
    __syncthreads();
  }
#pragma unroll
  for (int j = 0; j < 4; ++j) {
    int s = q0 + wv * 4 + j;
    if (s < Ssz) out[((size_t)b * Ssz + s) * Dm + h * 64 + lane] = o4[j] * rcp[j];
  }
}

// ---------------- seq mean over S ----------------
__global__ __launch_bounds__(256) void seqmean_kernel(const float* __restrict__ xn,
                                                      float* __restrict__ seq) {
  int b = blockIdx.y;
  int d = blockIdx.x * 256 + threadIdx.x;
  float s = 0.f;
  for (int t = 0; t < Ssz; ++t) s += xn[((size_t)b * Ssz + t) * Dm + d];
  seq[b * Dm + d] = s * (1.f / 500.f);
}

// ---------------- gate: logits -> softmax -> top4 -> softmax weights (fp32) ----------------
__global__ __launch_bounds__(64) void gate_kernel(const float* __restrict__ g1,
                                                  const float* __restrict__ w2,
                                                  const float* __restrict__ b2,
                                                  int* __restrict__ idx_out,
                                                  float* __restrict__ w_out) {
  int b = blockIdx.x, lane = threadIdx.x;
  __shared__ float g1s[768];
  __shared__ float lg[16];
  for (int j = lane; j < 768; j += 64) g1s[j] = g1[b * 768 + j];
  __syncthreads();
  if (lane < 14) {
    float acc = b2[lane];
    for (int j = 0; j < 768; ++j) acc += g1s[j] * w2[(size_t)j * 14 + lane];
    lg[lane] = acc;
  }
  __syncthreads();
  if (lane == 0) {
    float m = lg[0];
    for (int e = 1; e < 14; ++e) m = fmaxf(m, lg[e]);
    float p[14]; float sm = 0.f;
    for (int e = 0; e < 14; ++e) { p[e] = expf(lg[e] - m); sm += p[e]; }
    for (int e = 0; e < 14; ++e) p[e] /= sm;
    bool used[14] = {};
    float tp[4]; int ti[4];
    for (int k = 0; k < 4; ++k) {
      float bv = -1.f; int bi = 0;
      for (int e = 0; e < 14; ++e)
        if (!used[e] && p[e] > bv) { bv = p[e]; bi = e; }
      used[bi] = true; tp[k] = bv; ti[k] = bi;
    }
    float s2 = 0.f; float wk[4];
    for (int k = 0; k < 4; ++k) { wk[k] = expf(tp[k] - tp[0]); s2 += wk[k]; }
    for (int k = 0; k < 4; ++k) { idx_out[b * 4 + k] = ti[k]; w_out[b * 4 + k] = wk[k] / s2; }
  }
}

extern "C" void kernel_launch(void* const* d_in, const int* in_sizes, int n_in,
                              void* d_out, int out_size, void* d_ws, size_t ws_size,
                              hipStream_t stream) {
  (void)in_sizes; (void)n_in; (void)out_size; (void)ws_size;
  const float* x       = (const float*)d_in[0];
  const float* conv_w  = (const float*)d_in[1];
  const float* conv_b  = (const float*)d_in[2];
  const float* pos     = (const float*)d_in[3];
  const float* ln1_s   = (const float*)d_in[4];
  const float* ln1_b   = (const float*)d_in[5];
  const float* w_qkv   = (const float*)d_in[6];
  const float* w_proj  = (const float*)d_in[7];
  const float* b_proj  = (const float*)d_in[8];
  const float* ln2_s   = (const float*)d_in[9];
  const float* ln2_b   = (const float*)d_in[10];
  const float* gate_w1 = (const float*)d_in[11];
  const float* gate_b1 = (const float*)d_in[12];
  const float* gate_w2 = (const float*)d_in[13];
  const float* gate_b2 = (const float*)d_in[14];
  const float* exp_w1  = (const float*)d_in[15];
  const float* exp_b1  = (const float*)d_in[16];
  const float* exp_w2  = (const float*)d_in[17];
  const float* exp_b2  = (const float*)d_in[18];
  const float* sh_w1   = (const float*)d_in[19];
  const float* sh_b1   = (const float*)d_in[20];
  const float* sh_w2   = (const float*)d_in[21];
  const float* sh_b2   = (const float*)d_in[22];
  const float* lnf_s   = (const float*)d_in[23];
  const float* lnf_b   = (const float*)d_in[24];

  float* ws = (float*)d_ws;
  size_t off = 0;
  auto alloc = [&](size_t n) { float* p = ws + off; off += (n + 63) & ~(size_t)63; return p; };
  // fp32 buffers
  float* tok  = alloc(12288000);   // (B*S, D) residual stream
  float* xn   = alloc(12288000);   // ln / attn output
  float* regA = alloc(36864000);   // qkv fp32 (16000x2304); reused as hid fp16 pair after attn
  // fp16 activation pair (as float-sized carve: 16000*768 halves each)
  _Float16* xh = (_Float16*)alloc(6144000);
  _Float16* xl = (_Float16*)alloc(6144000);
  // fp16 transposed weights (per layer, reused)
  _Float16* wqkvT = (_Float16*)alloc(884736);    // [2304][768]
  _Float16* wprojT= (_Float16*)alloc(294912);    // [768][768]
  _Float16* shw1T = (_Float16*)alloc(1179648);   // [3072][768]
  _Float16* shw2T = (_Float16*)alloc(1179648);   // [768][3072]
  _Float16* ew1T  = (_Float16*)alloc(8257536);   // 14 x [1536][768]
  _Float16* ew2T  = (_Float16*)alloc(8257536);   // 14 x [768][1536]
  float* seq  = alloc(32 * 768);
  float* g1   = alloc(32 * 768);
  float* wgt  = alloc(128);
  int*   idx  = (int*)alloc(128);
  // hid pair carved from regA (qkv dead after attn; hid live only in FFN/MoE phase)
  _Float16* hidh = (_Float16*)regA;                    // 16000*1536 halves
  _Float16* hidl = (_Float16*)(regA + 12288000);       // 16000*1536 halves

  const int M = 16000;  // B*S
  conv_kernel<<<dim3(32, 32), 256, 0, stream>>>(x, conv_w, conv_b, pos, tok);
  for (int l = 0; l < 4; ++l) {
    // weight fp16 transposes for this layer
    wt_kernel<<<dim3(72, 24), 256, 0, stream>>>(w_qkv + (size_t)l * 768 * 2304, wqkvT, 768, 2304);
    wt_kernel<<<dim3(24, 24), 256, 0, stream>>>(w_proj + (size_t)l * 768 * 768, wprojT, 768, 768);
    wt_kernel<<<dim3(96, 24), 256, 0, stream>>>(sh_w1 + (size_t)l * 768 * 3072, shw1T, 768, 3072);
    wt_kernel<<<dim3(24, 96), 256, 0, stream>>>(sh_w2 + (size_t)l * 3072 * 768, shw2T, 3072, 768);
    wt_kernel<<<dim3(48, 24, 14), 256, 0, stream>>>(exp_w1 + (size_t)l * 14 * 768 * 1536, ew1T, 768, 1536);
    wt_kernel<<<dim3(24, 48, 14), 256, 0, stream>>>(exp_w2 + (size_t)l * 14 * 1536 * 768, ew2T, 1536, 768);

    ln_kernel<<<M, 256, 0, stream>>>(tok, ln1_s + l * 768, ln1_b + l * 768, xn);
    pairconv_kernel<<<12000, 256, 0, stream>>>(xn, xh, xl, 3072000);
    // qkv: [16000,2304] fp32 out for attention
    gemm16_kernel<<<dim3(18, 125), 256, 0, stream>>>(xh, xl, wqkvT, nullptr,
        regA, nullptr, nullptr, M, 768, 768, 768, 2304, 1.f, 0);
    attn_kernel<<<dim3(32, 12, 32), 256, 0, stream>>>(regA, xn);
    pairconv_kernel<<<12000, 256, 0, stream>>>(xn, xh, xl, 3072000);
    // proj += into tok
    gemm16_kernel<<<dim3(6, 125), 256, 0, stream>>>(xh, xl, wprojT, b_proj + l * 768,
        tok, nullptr, nullptr, M, 768, 768, 768, 768, 1.f, FLAG_BIAS | FLAG_ACC);

    ln_kernel<<<M, 256, 0, stream>>>(tok, ln2_s + l * 768, ln2_b + l * 768, xn);
    seqmean_kernel<<<dim3(3, 32), 256, 0, stream>>>(xn, seq);
    gemm_kernel<<<dim3(12, 1), 256, 0, stream>>>(seq, gate_w1 + (size_t)l * 768 * 768,
                                                 gate_b1 + l * 768, g1,
                                                 32, 768, 768, 768, 768, FLAG_BIAS | FLAG_GELU);
    gate_kernel<<<32, 64, 0, stream>>>(g1, gate_w2 + (size_t)l * 768 * 14, gate_b2 + l * 14,
                                       idx, wgt);
    pairconv_kernel<<<12000, 256, 0, stream>>>(xn, xh, xl, 3072000);
    // shared FFN in two 1536-wide chunks; second GEMM accumulates into tok directly
    for (int c = 0; c < 2; ++c) {
      int c0 = c * 1536;
      gemm16_kernel<<<dim3(12, 125), 256, 0, stream>>>(xh, xl,
          shw1T + (size_t)c0 * 768, sh_b1 + l * 3072 + c0,
          nullptr, hidh, hidl, M, 768, 768, 768, 1536, 1.f,
          FLAG_BIAS | FLAG_GELU | FLAG_PAIR);
      gemm16_kernel<<<dim3(6, 125), 256, 0, stream>>>(hidh, hidl,
          shw2T + c0, (c == 0) ? (sh_b2 + l * 768) : nullptr,
          tok, nullptr, nullptr, M, 1536, 1536, 3072, 768, 1.f,
          (c == 0) ? (FLAG_BIAS | FLAG_ACC) : FLAG_ACC);
    }
    // MoE: per-k expert GEMMs, accumulate weighted outputs into tok
    for (int k = 0; k < 4; ++k) {
      moe1_16_kernel<<<dim3(12, 4, 32), 256, 0, stream>>>(xh, xl, ew1T,
          exp_b1 + (size_t)l * 14 * 1536, idx, hidh, hidl, k);
      moe2_16_kernel<<<dim3(6, 4, 32), 256, 0, stream>>>(hidh, hidl, ew2T,
          exp_b2 + (size_t)l * 14 * 768, idx, wgt, tok, k);
    }
  }
  ln_kernel<<<M, 256, 0, stream>>>(tok, lnf_s, lnf_b, (float*)d_out);
}